// Round 9
// baseline (394.346 us; speedup 1.0000x reference)
//
#include <hip/hip_runtime.h>
#include <hip/hip_bf16.h>

// ---------------------------------------------------------------------------
// EncoderGNN: 3-layer GINE encoder, N=50000, E=800000, H=128.
// Round 9: agg processes 2 edges per wave -- lane = 4 channels of one edge
// (half=lane>>5 selects edge A/B, cg=lane&31 selects channel group). One
// dwordx2 gather instruction serves both edges; records stay wave-uniform
// (scalarized); channel math in f32x4 (v_pk_fma_f32). ~2x fewer VALU insts
// per edge. Cross-half combine via shfl_xor(32). Rest as round 8.
// ---------------------------------------------------------------------------

#define HDIM 128

typedef unsigned int uint32;
typedef unsigned short ushort16;
typedef __attribute__((ext_vector_type(8))) short short8;
typedef __attribute__((ext_vector_type(4))) float f32x4;

__device__ __forceinline__ ushort16 f2bf(float f) {
    uint32 u = __float_as_uint(f);
    u += 0x7fff + ((u >> 16) & 1);      // round-to-nearest-even
    return (ushort16)(u >> 16);
}
__device__ __forceinline__ float bflo(uint32 g) { return __uint_as_float(g << 16); }
__device__ __forceinline__ float bfhi(uint32 g) { return __uint_as_float(g & 0xffff0000u); }

// ---------------- CSR build ----------------
__global__ void count_kernel(const int* __restrict__ dstIdx, int* __restrict__ deg, int E) {
    int e = blockIdx.x * blockDim.x + threadIdx.x;
    if (e < E) atomicAdd(&deg[dstIdx[e]], 1);
}

__global__ __launch_bounds__(256) void partial_kernel(const int* __restrict__ deg,
                                                      int* __restrict__ partials, int N) {
    __shared__ int red[256];
    int i = blockIdx.x * 256 + threadIdx.x;
    red[threadIdx.x] = (i < N) ? deg[i] : 0;
    __syncthreads();
#pragma unroll
    for (int off = 128; off > 0; off >>= 1) {
        if (threadIdx.x < off) red[threadIdx.x] += red[threadIdx.x + off];
        __syncthreads();
    }
    if (threadIdx.x == 0) partials[blockIdx.x] = red[0];
}

__global__ __launch_bounds__(256) void scan_partials_kernel(const int* __restrict__ partials,
                                                            int* __restrict__ offsets,
                                                            int nb, int* __restrict__ row_ptr,
                                                            int N, int E) {
    __shared__ int buf[256];
    int tid = threadIdx.x;
    buf[tid] = (tid < nb) ? partials[tid] : 0;
    __syncthreads();
#pragma unroll
    for (int off = 1; off < 256; off <<= 1) {
        int v = (tid >= off) ? buf[tid - off] : 0;
        __syncthreads();
        buf[tid] += v;
        __syncthreads();
    }
    if (tid < nb) offsets[tid] = buf[tid] - partials[tid];   // exclusive
    if (tid == 0) row_ptr[N] = E;
}

__global__ __launch_bounds__(256) void scatter_scan_kernel(const int* __restrict__ deg,
                                                           const int* __restrict__ offsets,
                                                           int* __restrict__ row_ptr,
                                                           int* __restrict__ fill_ptr, int N) {
    __shared__ int buf[256];
    int tid = threadIdx.x;
    int i = blockIdx.x * 256 + tid;
    int v = (i < N) ? deg[i] : 0;
    buf[tid] = v;
    __syncthreads();
#pragma unroll
    for (int off = 1; off < 256; off <<= 1) {
        int t = (tid >= off) ? buf[tid - off] : 0;
        __syncthreads();
        buf[tid] += t;
        __syncthreads();
    }
    if (i < N) {
        int excl = buf[tid] - v + offsets[blockIdx.x];
        row_ptr[i]  = excl;
        fill_ptr[i] = excl;
    }
}

// one 16B record per edge: {src, ea01(bf16x2), ea23(bf16x2), 0}
__global__ void fill_kernel(const int* __restrict__ srcIdx, const int* __restrict__ dstIdx,
                            const float* __restrict__ edge_attr,
                            int* __restrict__ fill_ptr, int4* __restrict__ adj, int E) {
    int e = blockIdx.x * blockDim.x + threadIdx.x;
    if (e < E) {
        int d = dstIdx[e];
        int pos = atomicAdd(&fill_ptr[d], 1);
        float4 ea = *(const float4*)(edge_attr + (size_t)e * 4);
        int4 rec;
        rec.x = srcIdx[e];
        rec.y = (int)(((uint32)f2bf(ea.y) << 16) | (uint32)f2bf(ea.x));
        rec.z = (int)(((uint32)f2bf(ea.w) << 16) | (uint32)f2bf(ea.z));
        rec.w = 0;
        adj[pos] = rec;
    }
}

// ---------------- weight prep: bf16 + transpose (once per call) ----------------
__global__ void prep_weights(const float* __restrict__ W1, const float* __restrict__ W2,
                             ushort16* __restrict__ Wb1t, ushort16* __restrict__ Wb2t, int total) {
    int idx = blockIdx.x * 256 + threadIdx.x;
    if (idx >= total) return;
    int l = idx >> 14;
    int rem = idx & 16383;
    int n = rem >> 7, k = rem & 127;
    size_t src = (size_t)l * 16384 + (size_t)k * 128 + n;
    size_t dst = (size_t)l * 16384 + (size_t)n * 128 + k;
    Wb1t[dst] = f2bf(W1[src]);
    Wb2t[dst] = f2bf(W2[src]);
}

// ---------------- node embedding (writes bf16 h) ----------------
__global__ void embed_kernel(const int* __restrict__ x_type, const float* __restrict__ x_feat,
                             const float* __restrict__ type_embed, const float* __restrict__ featW,
                             const float* __restrict__ featb, ushort16* __restrict__ h, int N) {
    int idx = blockIdx.x * 256 + threadIdx.x;
    int n = idx >> 7, c = idx & 127;
    if (n >= N) return;
    int t = x_type[n];
    float acc = type_embed[(size_t)t * HDIM + c] + featb[c];
#pragma unroll
    for (int k = 0; k < 7; ++k)
        acc = fmaf(x_feat[(size_t)n * 7 + k], featW[(size_t)k * HDIM + c], acc);
    h[(size_t)n * HDIM + c] = f2bf(acc);
}

// ---------------- aggregation: 2 edges/wave, 4 channels/lane, persistent ----------------
__global__ __launch_bounds__(128) void agg_kernel(
        const uint32* __restrict__ hq,       // [N][64] packed bf16x2
        const int* __restrict__ row_ptr,
        const int4* __restrict__ adj,        // 16B records (uniform per wave)
        const float* __restrict__ edgeW, const float* __restrict__ edgeb,
        const float* __restrict__ eps, int l, uint32* __restrict__ zq, int N) {
    const int lane = threadIdx.x & 63;
    const int half = lane >> 5;          // which edge of the pair
    const int cg   = lane & 31;          // channel group: channels 4*cg..4*cg+3
    const int wid  = blockIdx.x * 2 + (threadIdx.x >> 6);
    const int nw   = gridDim.x * 2;

    const int c0 = 4 * cg;
    const f32x4 w0 = *(const f32x4*)(edgeW + c0);
    const f32x4 w1 = *(const f32x4*)(edgeW + 128 + c0);
    const f32x4 w2 = *(const f32x4*)(edgeW + 256 + c0);
    const f32x4 w3 = *(const f32x4*)(edgeW + 384 + c0);
    const f32x4 eb = *(const f32x4*)(edgeb + c0);
    const float ep = 1.0f + eps[l];

    // m = relu(h_src + ea@edgeW + eb) for this lane's 4 channels of its edge
#define EDGEQ(EY, EZ, G, ACC) {                                               \
        float a0 = bflo(EY), a1 = bfhi(EY), a2 = bflo(EZ), a3 = bfhi(EZ);     \
        f32x4 e = eb;                                                         \
        e += a0 * w0;  e += a1 * w1;  e += a2 * w2;  e += a3 * w3;            \
        float m0 = bflo((G).x) + e.x, m1 = bfhi((G).x) + e.y;                 \
        float m2 = bflo((G).y) + e.z, m3 = bfhi((G).y) + e.w;                 \
        ACC.x += fmaxf(m0, 0.f); ACC.y += fmaxf(m1, 0.f);                     \
        ACC.z += fmaxf(m2, 0.f); ACC.w += fmaxf(m3, 0.f);                     \
    }

    for (int node = wid; node < N; node += nw) {
        const int beg = __builtin_amdgcn_readfirstlane(row_ptr[node]);
        const int end = __builtin_amdgcn_readfirstlane(row_ptr[node + 1]);
        const uint2 gs = *(const uint2*)(hq + (size_t)node * 64 + 2 * cg); // self, early

        f32x4 accA = {0.f, 0.f, 0.f, 0.f}, accB = {0.f, 0.f, 0.f, 0.f};
        int i = beg;
        // 4 pairs (8 edges) per iteration: 4 gathers in flight
        for (; i + 8 <= end; i += 8) {
            int4 qa0 = adj[i + 0], qb0 = adj[i + 1];
            int4 qa1 = adj[i + 2], qb1 = adj[i + 3];
            int4 qa2 = adj[i + 4], qb2 = adj[i + 5];
            int4 qa3 = adj[i + 6], qb3 = adj[i + 7];
            int s0 = half ? qb0.x : qa0.x;
            int s1 = half ? qb1.x : qa1.x;
            int s2 = half ? qb2.x : qa2.x;
            int s3 = half ? qb3.x : qa3.x;
            uint2 g0 = *(const uint2*)(hq + (size_t)s0 * 64 + 2 * cg);
            uint2 g1 = *(const uint2*)(hq + (size_t)s1 * 64 + 2 * cg);
            uint2 g2 = *(const uint2*)(hq + (size_t)s2 * 64 + 2 * cg);
            uint2 g3 = *(const uint2*)(hq + (size_t)s3 * 64 + 2 * cg);
            uint32 y0 = (uint32)(half ? qb0.y : qa0.y), z0 = (uint32)(half ? qb0.z : qa0.z);
            uint32 y1 = (uint32)(half ? qb1.y : qa1.y), z1 = (uint32)(half ? qb1.z : qa1.z);
            uint32 y2 = (uint32)(half ? qb2.y : qa2.y), z2 = (uint32)(half ? qb2.z : qa2.z);
            uint32 y3 = (uint32)(half ? qb3.y : qa3.y), z3 = (uint32)(half ? qb3.z : qa3.z);
            EDGEQ(y0, z0, g0, accA);
            EDGEQ(y1, z1, g1, accB);
            EDGEQ(y2, z2, g2, accA);
            EDGEQ(y3, z3, g3, accB);
        }
        for (; i + 2 <= end; i += 2) {
            int4 qa = adj[i], qb = adj[i + 1];
            int s = half ? qb.x : qa.x;
            uint2 g = *(const uint2*)(hq + (size_t)s * 64 + 2 * cg);
            uint32 y = (uint32)(half ? qb.y : qa.y), z = (uint32)(half ? qb.z : qa.z);
            EDGEQ(y, z, g, accA);
        }
        if (i < end) {   // odd leftover edge: half-0 lanes own it
            int4 q = adj[i];
            uint2 g = *(const uint2*)(hq + (size_t)q.x * 64 + 2 * cg);
            float a0 = bflo((uint32)q.y), a1 = bfhi((uint32)q.y);
            float a2 = bflo((uint32)q.z), a3 = bfhi((uint32)q.z);
            f32x4 e = eb;
            e += a0 * w0;  e += a1 * w1;  e += a2 * w2;  e += a3 * w3;
            float m0 = fmaxf(bflo(g.x) + e.x, 0.f);
            float m1 = fmaxf(bfhi(g.x) + e.y, 0.f);
            float m2 = fmaxf(bflo(g.y) + e.z, 0.f);
            float m3 = fmaxf(bfhi(g.y) + e.w, 0.f);
            float keep = (half == 0) ? 1.f : 0.f;
            accB.x += keep * m0; accB.y += keep * m1;
            accB.z += keep * m2; accB.w += keep * m3;
        }

        f32x4 tot = accA + accB;
        // combine the two edge-halves: lane l <-> lane l+32 hold same channels
        tot.x += __shfl_xor(tot.x, 32, 64);
        tot.y += __shfl_xor(tot.y, 32, 64);
        tot.z += __shfl_xor(tot.z, 32, 64);
        tot.w += __shfl_xor(tot.w, 32, 64);

        if (half == 0) {
            float z0 = fmaf(ep, bflo(gs.x), tot.x);
            float z1 = fmaf(ep, bfhi(gs.x), tot.y);
            float z2 = fmaf(ep, bflo(gs.y), tot.z);
            float z3 = fmaf(ep, bfhi(gs.y), tot.w);
            uint2 o;
            o.x = ((uint32)f2bf(z1) << 16) | (uint32)f2bf(z0);
            o.y = ((uint32)f2bf(z3) << 16) | (uint32)f2bf(z2);
            *(uint2*)(zq + (size_t)node * 64 + 2 * cg) = o;
        }
    }
#undef EDGEQ
}

// ---------------- MFMA MLP, operand-swapped ----------------
#define T_STRIDE 136   // shorts; 272B rows: 16B-aligned for b128 reads
__global__ __launch_bounds__(256) void mlp_mfma(
        const ushort16* __restrict__ zq,     // [N64][128] bf16
        const ushort16* __restrict__ Wb1t,   // [128 n][128 k] bf16
        const float* __restrict__ b1,
        const ushort16* __restrict__ Wb2t,
        const float* __restrict__ b2,
        ushort16* __restrict__ h_out, int N) {
    __shared__ ushort16 t_lds[64 * T_STRIDE];
    const int tid = threadIdx.x;
    const int w = tid >> 6, lane = tid & 63;
    const int c = lane & 15, g = lane >> 4;
    const int wrow0 = blockIdx.x * 64 + w * 16;   // node-tile base for this wave

    // ---- GEMM1: t^T = W1^T @ z^T ----
    const ushort16* zrow = zq + (size_t)(wrow0 + c) * HDIM + g * 8;
    short8 bf[4];
#pragma unroll
    for (int kk = 0; kk < 4; ++kk)
        bf[kk] = *(const short8*)(zrow + kk * 32);

    f32x4 acc[8];
#pragma unroll
    for (int n = 0; n < 8; ++n) {
        float4 bb = *(const float4*)(b1 + n * 16 + g * 4);
        acc[n] = (f32x4){bb.x, bb.y, bb.z, bb.w};
    }
#pragma unroll
    for (int kk = 0; kk < 4; ++kk) {
#pragma unroll
        for (int n = 0; n < 8; ++n) {
            short8 af = *(const short8*)(Wb1t + (size_t)(n * 16 + c) * HDIM + kk * 32 + g * 8);
            acc[n] = __builtin_amdgcn_mfma_f32_16x16x32_bf16(af, bf[kk], acc[n], 0, 0, 0);
        }
    }
#pragma unroll
    for (int n = 0; n < 8; ++n) {
        ushort4 u;
        u.x = f2bf(fmaxf(acc[n][0], 0.f));
        u.y = f2bf(fmaxf(acc[n][1], 0.f));
        u.z = f2bf(fmaxf(acc[n][2], 0.f));
        u.w = f2bf(fmaxf(acc[n][3], 0.f));
        *(ushort4*)(&t_lds[(w * 16 + c) * T_STRIDE + n * 16 + g * 4]) = u;
    }
    __syncthreads();

    // ---- GEMM2: h^T = W2^T @ t^T ----
    short8 bf2[4];
#pragma unroll
    for (int kk = 0; kk < 4; ++kk)
        bf2[kk] = *(const short8*)(&t_lds[(w * 16 + c) * T_STRIDE + kk * 32 + g * 8]);

    f32x4 acc2[8];
#pragma unroll
    for (int n = 0; n < 8; ++n) {
        float4 bb = *(const float4*)(b2 + n * 16 + g * 4);
        acc2[n] = (f32x4){bb.x, bb.y, bb.z, bb.w};
    }
#pragma unroll
    for (int kk = 0; kk < 4; ++kk) {
#pragma unroll
        for (int n = 0; n < 8; ++n) {
            short8 af = *(const short8*)(Wb2t + (size_t)(n * 16 + c) * HDIM + kk * 32 + g * 8);
            acc2[n] = __builtin_amdgcn_mfma_f32_16x16x32_bf16(af, bf2[kk], acc2[n], 0, 0, 0);
        }
    }
    if (wrow0 + c < N) {
#pragma unroll
        for (int n = 0; n < 8; ++n) {
            ushort4 u;
            u.x = f2bf(fmaxf(acc2[n][0], 0.f));
            u.y = f2bf(fmaxf(acc2[n][1], 0.f));
            u.z = f2bf(fmaxf(acc2[n][2], 0.f));
            u.w = f2bf(fmaxf(acc2[n][3], 0.f));
            *(ushort4*)(h_out + (size_t)(wrow0 + c) * HDIM + n * 16 + g * 4) = u;
        }
    }
}

// ---------------- output projection (reads bf16 h) ----------------
__global__ void out_kernel(const uint32* __restrict__ hq, const float* __restrict__ Wout,
                           const float* __restrict__ bout, float* __restrict__ out, int N) {
    int idx = blockIdx.x * 256 + threadIdx.x;
    int n = idx >> 4, pe = idx & 15;
    if (n >= N) return;
    float acc = bout[pe];
#pragma unroll 8
    for (int k2 = 0; k2 < 64; ++k2) {
        uint32 g = hq[(size_t)n * 64 + k2];
        acc = fmaf(bflo(g), Wout[(2 * k2) * 16 + pe], acc);
        acc = fmaf(bfhi(g), Wout[(2 * k2 + 1) * 16 + pe], acc);
    }
    out[(size_t)n * 16 + pe] = acc;
}

extern "C" void kernel_launch(void* const* d_in, const int* in_sizes, int n_in,
                              void* d_out, int out_size, void* d_ws, size_t ws_size,
                              hipStream_t stream) {
    const int*   x_type     = (const int*)  d_in[0];
    const float* x_feat     = (const float*)d_in[1];
    const int*   edge_index = (const int*)  d_in[2];
    const float* edge_attr  = (const float*)d_in[3];
    const float* type_embed = (const float*)d_in[4];
    const float* featW      = (const float*)d_in[5];
    const float* featb      = (const float*)d_in[6];
    const float* edgeW      = (const float*)d_in[7];
    const float* edgeb      = (const float*)d_in[8];
    const float* W1         = (const float*)d_in[9];
    const float* b1         = (const float*)d_in[10];
    const float* W2         = (const float*)d_in[11];
    const float* b2         = (const float*)d_in[12];
    const float* eps        = (const float*)d_in[13];
    const float* Wout       = (const float*)d_in[14];
    const float* bout       = (const float*)d_in[15];

    const int N = in_sizes[0];
    const int E = in_sizes[2] / 2;
    const int L = in_sizes[13];
    const int N64 = (N + 63) & ~63;     // pad node buffers so MFMA tiles read in-bounds

    const int* srcIdx = edge_index;
    const int* dstIdx = edge_index + E;

    auto align256 = [](size_t x) { return (x + 255) & ~(size_t)255; };
    char* p = (char*)d_ws;
    ushort16* h_buf  = (ushort16*)p;           p += align256((size_t)N64 * HDIM * 2);
    ushort16* z_buf  = (ushort16*)p;           p += align256((size_t)N64 * HDIM * 2);
    int*   deg       = (int*)p;                p += align256((size_t)N * 4);
    int*   row_ptr   = (int*)p;                p += align256((size_t)(N + 1) * 4);
    int*   fill_ptr  = (int*)p;                p += align256((size_t)N * 4);
    int4*  adj       = (int4*)p;               p += align256((size_t)E * 16);
    int*   partials  = (int*)p;                p += align256(512 * 4);
    int*   offsets   = (int*)p;                p += align256(512 * 4);
    ushort16* Wb1t   = (ushort16*)p;           p += align256((size_t)L * HDIM * HDIM * 2);
    ushort16* Wb2t   = (ushort16*)p;           p += align256((size_t)L * HDIM * HDIM * 2);
    (void)ws_size;

    const int nb = (N + 255) / 256;   // 196 <= 256

    hipMemsetAsync(deg, 0, (size_t)N * 4, stream);
    count_kernel<<<(E + 255) / 256, 256, 0, stream>>>(dstIdx, deg, E);
    partial_kernel<<<nb, 256, 0, stream>>>(deg, partials, N);
    scan_partials_kernel<<<1, 256, 0, stream>>>(partials, offsets, nb, row_ptr, N, E);
    scatter_scan_kernel<<<nb, 256, 0, stream>>>(deg, offsets, row_ptr, fill_ptr, N);
    fill_kernel<<<(E + 255) / 256, 256, 0, stream>>>(srcIdx, dstIdx, edge_attr,
                                                     fill_ptr, adj, E);

    const int wtotal = L * HDIM * HDIM;
    prep_weights<<<(wtotal + 255) / 256, 256, 0, stream>>>(W1, W2, Wb1t, Wb2t, wtotal);

    embed_kernel<<<((size_t)N * HDIM + 255) / 256, 256, 0, stream>>>(
        x_type, x_feat, type_embed, featW, featb, h_buf, N);

    for (int l = 0; l < L; ++l) {
        agg_kernel<<<4096, 128, 0, stream>>>(
            (const uint32*)h_buf, row_ptr, adj, edgeW, edgeb, eps, l,
            (uint32*)z_buf, N);
        mlp_mfma<<<N64 / 64, 256, 0, stream>>>(
            z_buf, Wb1t + (size_t)l * HDIM * HDIM, b1 + (size_t)l * HDIM,
            Wb2t + (size_t)l * HDIM * HDIM, b2 + (size_t)l * HDIM, h_buf, N);
    }

    out_kernel<<<((size_t)N * 16 + 255) / 256, 256, 0, stream>>>(
        (const uint32*)h_buf, Wout, bout, (float*)d_out, N);
}

// Round 10
// 371.056 us; speedup vs baseline: 1.0628x; 1.0628x over previous
//
#include <hip/hip_runtime.h>
#include <hip/hip_bf16.h>

// ---------------------------------------------------------------------------
// EncoderGNN: 3-layer GINE encoder, N=50000, E=800000, H=128.
// Round 10: revert to round-6 agg structure (1 wave/node, 25k x 128-thd
// blocks, scalarized edge loop -- best measured). Edge record widened to 32B
// {src, ea as 4 x f32}: fill stays line-bound (1 line/edge, same WRITE_SIZE)
// but agg loses all ea bf16 unpacks -- ea lives in SGPRs and feeds
// v_fma_f32 v,s,v,v directly. ~24 -> ~16 VALU insts/edge.
// ---------------------------------------------------------------------------

#define HDIM 128

typedef unsigned int uint32;
typedef unsigned short ushort16;
typedef __attribute__((ext_vector_type(8))) short short8;
typedef __attribute__((ext_vector_type(4))) float f32x4;
typedef __attribute__((ext_vector_type(2))) float f32x2;

__device__ __forceinline__ ushort16 f2bf(float f) {
    uint32 u = __float_as_uint(f);
    u += 0x7fff + ((u >> 16) & 1);      // round-to-nearest-even
    return (ushort16)(u >> 16);
}
__device__ __forceinline__ float bflo(uint32 g) { return __uint_as_float(g << 16); }
__device__ __forceinline__ float bfhi(uint32 g) { return __uint_as_float(g & 0xffff0000u); }

// ---------------- CSR build ----------------
__global__ void count_kernel(const int* __restrict__ dstIdx, int* __restrict__ deg, int E) {
    int e = blockIdx.x * blockDim.x + threadIdx.x;
    if (e < E) atomicAdd(&deg[dstIdx[e]], 1);
}

__global__ __launch_bounds__(256) void partial_kernel(const int* __restrict__ deg,
                                                      int* __restrict__ partials, int N) {
    __shared__ int red[256];
    int i = blockIdx.x * 256 + threadIdx.x;
    red[threadIdx.x] = (i < N) ? deg[i] : 0;
    __syncthreads();
#pragma unroll
    for (int off = 128; off > 0; off >>= 1) {
        if (threadIdx.x < off) red[threadIdx.x] += red[threadIdx.x + off];
        __syncthreads();
    }
    if (threadIdx.x == 0) partials[blockIdx.x] = red[0];
}

__global__ __launch_bounds__(256) void scan_partials_kernel(const int* __restrict__ partials,
                                                            int* __restrict__ offsets,
                                                            int nb, int* __restrict__ row_ptr,
                                                            int N, int E) {
    __shared__ int buf[256];
    int tid = threadIdx.x;
    buf[tid] = (tid < nb) ? partials[tid] : 0;
    __syncthreads();
#pragma unroll
    for (int off = 1; off < 256; off <<= 1) {
        int v = (tid >= off) ? buf[tid - off] : 0;
        __syncthreads();
        buf[tid] += v;
        __syncthreads();
    }
    if (tid < nb) offsets[tid] = buf[tid] - partials[tid];   // exclusive
    if (tid == 0) row_ptr[N] = E;
}

__global__ __launch_bounds__(256) void scatter_scan_kernel(const int* __restrict__ deg,
                                                           const int* __restrict__ offsets,
                                                           int* __restrict__ row_ptr,
                                                           int* __restrict__ fill_ptr, int N) {
    __shared__ int buf[256];
    int tid = threadIdx.x;
    int i = blockIdx.x * 256 + tid;
    int v = (i < N) ? deg[i] : 0;
    buf[tid] = v;
    __syncthreads();
#pragma unroll
    for (int off = 1; off < 256; off <<= 1) {
        int t = (tid >= off) ? buf[tid - off] : 0;
        __syncthreads();
        buf[tid] += t;
        __syncthreads();
    }
    if (i < N) {
        int excl = buf[tid] - v + offsets[blockIdx.x];
        row_ptr[i]  = excl;
        fill_ptr[i] = excl;
    }
}

// one 32B record per edge: {src, ea0, ea1, ea2} {ea3, 0, 0, 0}
__global__ void fill_kernel(const int* __restrict__ srcIdx, const int* __restrict__ dstIdx,
                            const float* __restrict__ edge_attr,
                            int* __restrict__ fill_ptr, int4* __restrict__ adj, int E) {
    int e = blockIdx.x * blockDim.x + threadIdx.x;
    if (e < E) {
        int d = dstIdx[e];
        int pos = atomicAdd(&fill_ptr[d], 1);
        float4 ea = *(const float4*)(edge_attr + (size_t)e * 4);
        int4 r0, r1;
        r0.x = srcIdx[e];
        r0.y = __float_as_int(ea.x);
        r0.z = __float_as_int(ea.y);
        r0.w = __float_as_int(ea.z);
        r1.x = __float_as_int(ea.w);
        r1.y = 0; r1.z = 0; r1.w = 0;
        adj[2 * (size_t)pos]     = r0;
        adj[2 * (size_t)pos + 1] = r1;
    }
}

// ---------------- weight prep: bf16 + transpose (once per call) ----------------
__global__ void prep_weights(const float* __restrict__ W1, const float* __restrict__ W2,
                             ushort16* __restrict__ Wb1t, ushort16* __restrict__ Wb2t, int total) {
    int idx = blockIdx.x * 256 + threadIdx.x;
    if (idx >= total) return;
    int l = idx >> 14;
    int rem = idx & 16383;
    int n = rem >> 7, k = rem & 127;
    size_t src = (size_t)l * 16384 + (size_t)k * 128 + n;
    size_t dst = (size_t)l * 16384 + (size_t)n * 128 + k;
    Wb1t[dst] = f2bf(W1[src]);
    Wb2t[dst] = f2bf(W2[src]);
}

// ---------------- node embedding (writes bf16 h) ----------------
__global__ void embed_kernel(const int* __restrict__ x_type, const float* __restrict__ x_feat,
                             const float* __restrict__ type_embed, const float* __restrict__ featW,
                             const float* __restrict__ featb, ushort16* __restrict__ h, int N) {
    int idx = blockIdx.x * 256 + threadIdx.x;
    int n = idx >> 7, c = idx & 127;
    if (n >= N) return;
    int t = x_type[n];
    float acc = type_embed[(size_t)t * HDIM + c] + featb[c];
#pragma unroll
    for (int k = 0; k < 7; ++k)
        acc = fmaf(x_feat[(size_t)n * 7 + k], featW[(size_t)k * HDIM + c], acc);
    h[(size_t)n * HDIM + c] = f2bf(acc);
}

// ---------------- aggregation: 1 wave/node, scalarized loop, f32 ea in SGPRs --------
__global__ __launch_bounds__(128) void agg_kernel(
        const uint32* __restrict__ hq,       // [N][64] packed bf16x2
        const int* __restrict__ row_ptr,
        const int4* __restrict__ adj,        // 32B records (uniform per wave)
        const float* __restrict__ edgeW, const float* __restrict__ edgeb,
        const float* __restrict__ eps, int l, uint32* __restrict__ zq, int N) {
    const int node = blockIdx.x * 2 + (threadIdx.x >> 6);
    const int lane = threadIdx.x & 63;
    if (node >= N) return;
    const int c0 = 2 * lane;
    const f32x2 w0 = {edgeW[c0],       edgeW[c0 + 1]};
    const f32x2 w1 = {edgeW[128 + c0], edgeW[128 + c0 + 1]};
    const f32x2 w2 = {edgeW[256 + c0], edgeW[256 + c0 + 1]};
    const f32x2 w3 = {edgeW[384 + c0], edgeW[384 + c0 + 1]};
    const f32x2 eb = {edgeb[c0],       edgeb[c0 + 1]};

    // wave-uniform bounds -> SGPR (adj records via s_load; gathers saddr-form)
    const int beg = __builtin_amdgcn_readfirstlane(row_ptr[node]);
    const int end = __builtin_amdgcn_readfirstlane(row_ptr[node + 1]);

    const uint32 gs = hq[(size_t)node * 64 + lane];   // self-term early

    f32x2 accA = {0.f, 0.f}, accB = {0.f, 0.f};

    // Q0 = {src, ea0, ea1, ea2}, Q1 = {ea3, ...}; all wave-uniform scalars.
#define EDGE(Q0, Q1, G, ACC) {                                                \
        float a0 = __int_as_float((Q0).y);                                    \
        float a1 = __int_as_float((Q0).z);                                    \
        float a2 = __int_as_float((Q0).w);                                    \
        float a3 = __int_as_float((Q1).x);                                    \
        f32x2 e = eb;                                                         \
        e.x = fmaf(a0, w0.x, e.x);  e.y = fmaf(a0, w0.y, e.y);                \
        e.x = fmaf(a1, w1.x, e.x);  e.y = fmaf(a1, w1.y, e.y);                \
        e.x = fmaf(a2, w2.x, e.x);  e.y = fmaf(a2, w2.y, e.y);                \
        e.x = fmaf(a3, w3.x, e.x);  e.y = fmaf(a3, w3.y, e.y);                \
        ACC.x += fmaxf(bflo(G) + e.x, 0.f);                                   \
        ACC.y += fmaxf(bfhi(G) + e.y, 0.f);                                   \
    }

    int i = beg;
    for (; i + 8 <= end; i += 8) {
        int4 p0 = adj[2*(size_t)(i+0)], q0 = adj[2*(size_t)(i+0)+1];
        int4 p1 = adj[2*(size_t)(i+1)], q1 = adj[2*(size_t)(i+1)+1];
        int4 p2 = adj[2*(size_t)(i+2)], q2 = adj[2*(size_t)(i+2)+1];
        int4 p3 = adj[2*(size_t)(i+3)], q3 = adj[2*(size_t)(i+3)+1];
        int4 p4 = adj[2*(size_t)(i+4)], q4 = adj[2*(size_t)(i+4)+1];
        int4 p5 = adj[2*(size_t)(i+5)], q5 = adj[2*(size_t)(i+5)+1];
        int4 p6 = adj[2*(size_t)(i+6)], q6 = adj[2*(size_t)(i+6)+1];
        int4 p7 = adj[2*(size_t)(i+7)], q7 = adj[2*(size_t)(i+7)+1];
        uint32 g0 = hq[(size_t)p0.x * 64 + lane];
        uint32 g1 = hq[(size_t)p1.x * 64 + lane];
        uint32 g2 = hq[(size_t)p2.x * 64 + lane];
        uint32 g3 = hq[(size_t)p3.x * 64 + lane];
        uint32 g4 = hq[(size_t)p4.x * 64 + lane];
        uint32 g5 = hq[(size_t)p5.x * 64 + lane];
        uint32 g6 = hq[(size_t)p6.x * 64 + lane];
        uint32 g7 = hq[(size_t)p7.x * 64 + lane];
        EDGE(p0, q0, g0, accA); EDGE(p1, q1, g1, accB);
        EDGE(p2, q2, g2, accA); EDGE(p3, q3, g3, accB);
        EDGE(p4, q4, g4, accA); EDGE(p5, q5, g5, accB);
        EDGE(p6, q6, g6, accA); EDGE(p7, q7, g7, accB);
    }
    for (; i + 4 <= end; i += 4) {
        int4 p0 = adj[2*(size_t)(i+0)], q0 = adj[2*(size_t)(i+0)+1];
        int4 p1 = adj[2*(size_t)(i+1)], q1 = adj[2*(size_t)(i+1)+1];
        int4 p2 = adj[2*(size_t)(i+2)], q2 = adj[2*(size_t)(i+2)+1];
        int4 p3 = adj[2*(size_t)(i+3)], q3 = adj[2*(size_t)(i+3)+1];
        uint32 g0 = hq[(size_t)p0.x * 64 + lane];
        uint32 g1 = hq[(size_t)p1.x * 64 + lane];
        uint32 g2 = hq[(size_t)p2.x * 64 + lane];
        uint32 g3 = hq[(size_t)p3.x * 64 + lane];
        EDGE(p0, q0, g0, accA); EDGE(p1, q1, g1, accB);
        EDGE(p2, q2, g2, accA); EDGE(p3, q3, g3, accB);
    }
    for (; i < end; ++i) {
        int4 p = adj[2*(size_t)i], q = adj[2*(size_t)i + 1];
        uint32 g = hq[(size_t)p.x * 64 + lane];
        EDGE(p, q, g, accA);
    }
#undef EDGE

    const float ep = 1.0f + eps[l];
    float zl = fmaf(ep, bflo(gs), accA.x + accB.x);
    float zh = fmaf(ep, bfhi(gs), accA.y + accB.y);
    zq[(size_t)node * 64 + lane] = ((uint32)f2bf(zh) << 16) | (uint32)f2bf(zl);
}

// ---------------- MFMA MLP, operand-swapped ----------------
#define T_STRIDE 136   // shorts; 272B rows: 16B-aligned for b128 reads
__global__ __launch_bounds__(256) void mlp_mfma(
        const ushort16* __restrict__ zq,     // [N64][128] bf16
        const ushort16* __restrict__ Wb1t,   // [128 n][128 k] bf16
        const float* __restrict__ b1,
        const ushort16* __restrict__ Wb2t,
        const float* __restrict__ b2,
        ushort16* __restrict__ h_out, int N) {
    __shared__ ushort16 t_lds[64 * T_STRIDE];
    const int tid = threadIdx.x;
    const int w = tid >> 6, lane = tid & 63;
    const int c = lane & 15, g = lane >> 4;
    const int wrow0 = blockIdx.x * 64 + w * 16;   // node-tile base for this wave

    // ---- GEMM1: t^T = W1^T @ z^T ----
    const ushort16* zrow = zq + (size_t)(wrow0 + c) * HDIM + g * 8;
    short8 bf[4];
#pragma unroll
    for (int kk = 0; kk < 4; ++kk)
        bf[kk] = *(const short8*)(zrow + kk * 32);

    f32x4 acc[8];
#pragma unroll
    for (int n = 0; n < 8; ++n) {
        float4 bb = *(const float4*)(b1 + n * 16 + g * 4);
        acc[n] = (f32x4){bb.x, bb.y, bb.z, bb.w};
    }
#pragma unroll
    for (int kk = 0; kk < 4; ++kk) {
#pragma unroll
        for (int n = 0; n < 8; ++n) {
            short8 af = *(const short8*)(Wb1t + (size_t)(n * 16 + c) * HDIM + kk * 32 + g * 8);
            acc[n] = __builtin_amdgcn_mfma_f32_16x16x32_bf16(af, bf[kk], acc[n], 0, 0, 0);
        }
    }
#pragma unroll
    for (int n = 0; n < 8; ++n) {
        ushort4 u;
        u.x = f2bf(fmaxf(acc[n][0], 0.f));
        u.y = f2bf(fmaxf(acc[n][1], 0.f));
        u.z = f2bf(fmaxf(acc[n][2], 0.f));
        u.w = f2bf(fmaxf(acc[n][3], 0.f));
        *(ushort4*)(&t_lds[(w * 16 + c) * T_STRIDE + n * 16 + g * 4]) = u;
    }
    __syncthreads();

    // ---- GEMM2: h^T = W2^T @ t^T ----
    short8 bf2[4];
#pragma unroll
    for (int kk = 0; kk < 4; ++kk)
        bf2[kk] = *(const short8*)(&t_lds[(w * 16 + c) * T_STRIDE + kk * 32 + g * 8]);

    f32x4 acc2[8];
#pragma unroll
    for (int n = 0; n < 8; ++n) {
        float4 bb = *(const float4*)(b2 + n * 16 + g * 4);
        acc2[n] = (f32x4){bb.x, bb.y, bb.z, bb.w};
    }
#pragma unroll
    for (int kk = 0; kk < 4; ++kk) {
#pragma unroll
        for (int n = 0; n < 8; ++n) {
            short8 af = *(const short8*)(Wb2t + (size_t)(n * 16 + c) * HDIM + kk * 32 + g * 8);
            acc2[n] = __builtin_amdgcn_mfma_f32_16x16x32_bf16(af, bf2[kk], acc2[n], 0, 0, 0);
        }
    }
    if (wrow0 + c < N) {
#pragma unroll
        for (int n = 0; n < 8; ++n) {
            ushort4 u;
            u.x = f2bf(fmaxf(acc2[n][0], 0.f));
            u.y = f2bf(fmaxf(acc2[n][1], 0.f));
            u.z = f2bf(fmaxf(acc2[n][2], 0.f));
            u.w = f2bf(fmaxf(acc2[n][3], 0.f));
            *(ushort4*)(h_out + (size_t)(wrow0 + c) * HDIM + n * 16 + g * 4) = u;
        }
    }
}

// ---------------- output projection (reads bf16 h) ----------------
__global__ void out_kernel(const uint32* __restrict__ hq, const float* __restrict__ Wout,
                           const float* __restrict__ bout, float* __restrict__ out, int N) {
    int idx = blockIdx.x * 256 + threadIdx.x;
    int n = idx >> 4, pe = idx & 15;
    if (n >= N) return;
    float acc = bout[pe];
#pragma unroll 8
    for (int k2 = 0; k2 < 64; ++k2) {
        uint32 g = hq[(size_t)n * 64 + k2];
        acc = fmaf(bflo(g), Wout[(2 * k2) * 16 + pe], acc);
        acc = fmaf(bfhi(g), Wout[(2 * k2 + 1) * 16 + pe], acc);
    }
    out[(size_t)n * 16 + pe] = acc;
}

extern "C" void kernel_launch(void* const* d_in, const int* in_sizes, int n_in,
                              void* d_out, int out_size, void* d_ws, size_t ws_size,
                              hipStream_t stream) {
    const int*   x_type     = (const int*)  d_in[0];
    const float* x_feat     = (const float*)d_in[1];
    const int*   edge_index = (const int*)  d_in[2];
    const float* edge_attr  = (const float*)d_in[3];
    const float* type_embed = (const float*)d_in[4];
    const float* featW      = (const float*)d_in[5];
    const float* featb      = (const float*)d_in[6];
    const float* edgeW      = (const float*)d_in[7];
    const float* edgeb      = (const float*)d_in[8];
    const float* W1         = (const float*)d_in[9];
    const float* b1         = (const float*)d_in[10];
    const float* W2         = (const float*)d_in[11];
    const float* b2         = (const float*)d_in[12];
    const float* eps        = (const float*)d_in[13];
    const float* Wout       = (const float*)d_in[14];
    const float* bout       = (const float*)d_in[15];

    const int N = in_sizes[0];
    const int E = in_sizes[2] / 2;
    const int L = in_sizes[13];
    const int N64 = (N + 63) & ~63;     // pad node buffers so MFMA tiles read in-bounds

    const int* srcIdx = edge_index;
    const int* dstIdx = edge_index + E;

    auto align256 = [](size_t x) { return (x + 255) & ~(size_t)255; };
    char* p = (char*)d_ws;
    ushort16* h_buf  = (ushort16*)p;           p += align256((size_t)N64 * HDIM * 2);
    ushort16* z_buf  = (ushort16*)p;           p += align256((size_t)N64 * HDIM * 2);
    int*   deg       = (int*)p;                p += align256((size_t)N * 4);
    int*   row_ptr   = (int*)p;                p += align256((size_t)(N + 1) * 4);
    int*   fill_ptr  = (int*)p;                p += align256((size_t)N * 4);
    int4*  adj       = (int4*)p;               p += align256((size_t)E * 32);
    int*   partials  = (int*)p;                p += align256(512 * 4);
    int*   offsets   = (int*)p;                p += align256(512 * 4);
    ushort16* Wb1t   = (ushort16*)p;           p += align256((size_t)L * HDIM * HDIM * 2);
    ushort16* Wb2t   = (ushort16*)p;           p += align256((size_t)L * HDIM * HDIM * 2);
    (void)ws_size;

    const int nb = (N + 255) / 256;   // 196 <= 256

    hipMemsetAsync(deg, 0, (size_t)N * 4, stream);
    count_kernel<<<(E + 255) / 256, 256, 0, stream>>>(dstIdx, deg, E);
    partial_kernel<<<nb, 256, 0, stream>>>(deg, partials, N);
    scan_partials_kernel<<<1, 256, 0, stream>>>(partials, offsets, nb, row_ptr, N, E);
    scatter_scan_kernel<<<nb, 256, 0, stream>>>(deg, offsets, row_ptr, fill_ptr, N);
    fill_kernel<<<(E + 255) / 256, 256, 0, stream>>>(srcIdx, dstIdx, edge_attr,
                                                     fill_ptr, adj, E);

    const int wtotal = L * HDIM * HDIM;
    prep_weights<<<(wtotal + 255) / 256, 256, 0, stream>>>(W1, W2, Wb1t, Wb2t, wtotal);

    embed_kernel<<<((size_t)N * HDIM + 255) / 256, 256, 0, stream>>>(
        x_type, x_feat, type_embed, featW, featb, h_buf, N);

    for (int l = 0; l < L; ++l) {
        agg_kernel<<<(N + 1) / 2, 128, 0, stream>>>(
            (const uint32*)h_buf, row_ptr, adj, edgeW, edgeb, eps, l,
            (uint32*)z_buf, N);
        mlp_mfma<<<N64 / 64, 256, 0, stream>>>(
            z_buf, Wb1t + (size_t)l * HDIM * HDIM, b1 + (size_t)l * HDIM,
            Wb2t + (size_t)l * HDIM * HDIM, b2 + (size_t)l * HDIM, h_buf, N);
    }

    out_kernel<<<((size_t)N * 16 + 255) / 256, 256, 0, stream>>>(
        (const uint32*)h_buf, Wout, bout, (float*)d_out, N);
}

// Round 11
// 300.242 us; speedup vs baseline: 1.3134x; 1.2359x over previous
//
#include <hip/hip_runtime.h>
#include <hip/hip_bf16.h>

// ---------------------------------------------------------------------------
// EncoderGNN: 3-layer GINE encoder, N=50000, E=800000, H=128.
// Round 11: CSR build rewritten as 2-level counting sort (no global atomics):
//   hist(1024 chunks x 196 buckets, LDS) -> 3-kernel exclusive scan of the
//   [196][1024] matrix -> chunk scatter into bucket-contiguous tmp (writes
//   line-coalesced: ~4 records/bucket/chunk = full 64B lines) -> per-bucket
//   LDS sort emits row_ptr + final adj (64KB L2-resident window).
// agg = round-6 best (1 wave/node, scalarized loop, 16B records, bf16 ea).
// MFMA MLP operand-swapped; bf16 h/z everywhere.
// ---------------------------------------------------------------------------

#define HDIM 128
#define NCH 1024          // histogram chunks
#define NPB 256           // nodes per bucket

typedef unsigned int uint32;
typedef unsigned short ushort16;
typedef __attribute__((ext_vector_type(8))) short short8;
typedef __attribute__((ext_vector_type(4))) float f32x4;
typedef __attribute__((ext_vector_type(2))) float f32x2;

__device__ __forceinline__ ushort16 f2bf(float f) {
    uint32 u = __float_as_uint(f);
    u += 0x7fff + ((u >> 16) & 1);      // round-to-nearest-even
    return (ushort16)(u >> 16);
}
__device__ __forceinline__ float bflo(uint32 g) { return __uint_as_float(g << 16); }
__device__ __forceinline__ float bfhi(uint32 g) { return __uint_as_float(g & 0xffff0000u); }

// ---------------- CSR build: counting sort ----------------
// 1a: per-chunk histogram over buckets. histM[bucket][chunk].
__global__ __launch_bounds__(256) void hist_kernel(const int* __restrict__ dstIdx,
                                                   int* __restrict__ histM, int E, int NB) {
    __shared__ int hist[256];
    const int b = blockIdx.x;
    for (int j = threadIdx.x; j < NB; j += 256) hist[j] = 0;
    __syncthreads();
    const int epb = (E + NCH - 1) / NCH;
    const int e0 = b * epb, e1 = min(e0 + epb, E);
    for (int e = e0 + threadIdx.x; e < e1; e += 256)
        atomicAdd(&hist[dstIdx[e] >> 8], 1);
    __syncthreads();
    for (int j = threadIdx.x; j < NB; j += 256)
        histM[j * NCH + b] = hist[j];
}

// 1b: hierarchical exclusive scan of histM (length M = NB*NCH, bucket-major).
__global__ __launch_bounds__(256) void partial_kernel(const int* __restrict__ F,
                                                      int* __restrict__ partials, int M) {
    __shared__ int red[256];
    int i = blockIdx.x * 256 + threadIdx.x;
    red[threadIdx.x] = (i < M) ? F[i] : 0;
    __syncthreads();
#pragma unroll
    for (int off = 128; off > 0; off >>= 1) {
        if (threadIdx.x < off) red[threadIdx.x] += red[threadIdx.x + off];
        __syncthreads();
    }
    if (threadIdx.x == 0) partials[blockIdx.x] = red[0];
}

__global__ __launch_bounds__(1024) void scan_partials_kernel(const int* __restrict__ partials,
                                                             int* __restrict__ offsets, int nb) {
    __shared__ int buf[1024];
    int tid = threadIdx.x;
    int v0 = (tid < nb) ? partials[tid] : 0;
    buf[tid] = v0;
    __syncthreads();
#pragma unroll
    for (int off = 1; off < 1024; off <<= 1) {
        int v = (tid >= off) ? buf[tid - off] : 0;
        __syncthreads();
        buf[tid] += v;
        __syncthreads();
    }
    if (tid < nb) offsets[tid] = buf[tid] - v0;   // exclusive
}

__global__ __launch_bounds__(256) void excl_out_kernel(const int* __restrict__ F,
                                                       const int* __restrict__ offsets,
                                                       int* __restrict__ Fscan, int M) {
    __shared__ int buf[256];
    int tid = threadIdx.x;
    int i = blockIdx.x * 256 + tid;
    int v = (i < M) ? F[i] : 0;
    buf[tid] = v;
    __syncthreads();
#pragma unroll
    for (int off = 1; off < 256; off <<= 1) {
        int t = (tid >= off) ? buf[tid - off] : 0;
        __syncthreads();
        buf[tid] += t;
        __syncthreads();
    }
    if (i < M) Fscan[i] = buf[tid] - v + offsets[blockIdx.x];
}

// 1c: chunk scatter into bucket-contiguous tmp. rec = {src, ea01, ea23, dst}.
__global__ __launch_bounds__(256) void chunk_scatter_kernel(
        const int* __restrict__ srcIdx, const int* __restrict__ dstIdx,
        const float* __restrict__ edge_attr, const int* __restrict__ Fscan,
        int4* __restrict__ tmp, int E, int NB) {
    __shared__ int cur[256];
    const int b = blockIdx.x;
    for (int j = threadIdx.x; j < NB; j += 256) cur[j] = Fscan[j * NCH + b];
    __syncthreads();
    const int epb = (E + NCH - 1) / NCH;
    const int e0 = b * epb, e1 = min(e0 + epb, E);
    for (int e = e0 + threadIdx.x; e < e1; e += 256) {
        int d = dstIdx[e];
        int r = atomicAdd(&cur[d >> 8], 1);
        float4 ea = *(const float4*)(edge_attr + (size_t)e * 4);
        int4 rec;
        rec.x = srcIdx[e];
        rec.y = (int)(((uint32)f2bf(ea.y) << 16) | (uint32)f2bf(ea.x));
        rec.z = (int)(((uint32)f2bf(ea.w) << 16) | (uint32)f2bf(ea.z));
        rec.w = d;
        tmp[r] = rec;
    }
}

// 2: per-bucket sort -> row_ptr + final adj (keeps rec layout; agg ignores .w)
__global__ __launch_bounds__(256) void bucket_sort_kernel(
        const int4* __restrict__ tmp, const int* __restrict__ Fscan,
        int* __restrict__ row_ptr, int4* __restrict__ adj, int E, int NB, int N) {
    __shared__ int cnt[256];
    __shared__ int cur[256];
    const int bkt = blockIdx.x;
    const int tid = threadIdx.x;
    const int base = Fscan[bkt * NCH];
    const int endb = (bkt + 1 < NB) ? Fscan[(bkt + 1) * NCH] : E;

    cnt[tid] = 0;
    __syncthreads();
    for (int i = base + tid; i < endb; i += 256)
        atomicAdd(&cnt[tmp[i].w & 255], 1);
    __syncthreads();
    int orig = cnt[tid];
#pragma unroll
    for (int off = 1; off < 256; off <<= 1) {
        int v = (tid >= off) ? cnt[tid - off] : 0;
        __syncthreads();
        cnt[tid] += v;
        __syncthreads();
    }
    int excl = cnt[tid] - orig;
    int node = bkt * NPB + tid;
    if (node <= N) row_ptr[node] = base + excl;
    cur[tid] = base + excl;
    __syncthreads();
    for (int i = base + tid; i < endb; i += 256) {
        int4 rec = tmp[i];
        int pos = atomicAdd(&cur[rec.w & 255], 1);
        adj[pos] = rec;
    }
}

// ---------------- weight prep: bf16 + transpose (once per call) ----------------
__global__ void prep_weights(const float* __restrict__ W1, const float* __restrict__ W2,
                             ushort16* __restrict__ Wb1t, ushort16* __restrict__ Wb2t, int total) {
    int idx = blockIdx.x * 256 + threadIdx.x;
    if (idx >= total) return;
    int l = idx >> 14;
    int rem = idx & 16383;
    int n = rem >> 7, k = rem & 127;
    size_t src = (size_t)l * 16384 + (size_t)k * 128 + n;
    size_t dst = (size_t)l * 16384 + (size_t)n * 128 + k;
    Wb1t[dst] = f2bf(W1[src]);
    Wb2t[dst] = f2bf(W2[src]);
}

// ---------------- node embedding (writes bf16 h) ----------------
__global__ void embed_kernel(const int* __restrict__ x_type, const float* __restrict__ x_feat,
                             const float* __restrict__ type_embed, const float* __restrict__ featW,
                             const float* __restrict__ featb, ushort16* __restrict__ h, int N) {
    int idx = blockIdx.x * 256 + threadIdx.x;
    int n = idx >> 7, c = idx & 127;
    if (n >= N) return;
    int t = x_type[n];
    float acc = type_embed[(size_t)t * HDIM + c] + featb[c];
#pragma unroll
    for (int k = 0; k < 7; ++k)
        acc = fmaf(x_feat[(size_t)n * 7 + k], featW[(size_t)k * HDIM + c], acc);
    h[(size_t)n * HDIM + c] = f2bf(acc);
}

// ---------------- aggregation: round-6 form (best measured) ----------------
__global__ __launch_bounds__(128) void agg_kernel(
        const uint32* __restrict__ hq,       // [N][64] packed bf16x2
        const int* __restrict__ row_ptr,
        const int4* __restrict__ adj,        // 16B records (uniform per wave)
        const float* __restrict__ edgeW, const float* __restrict__ edgeb,
        const float* __restrict__ eps, int l, uint32* __restrict__ zq, int N) {
    const int node = blockIdx.x * 2 + (threadIdx.x >> 6);
    const int lane = threadIdx.x & 63;
    if (node >= N) return;
    const int c0 = 2 * lane;
    const f32x2 w0 = {edgeW[c0],       edgeW[c0 + 1]};
    const f32x2 w1 = {edgeW[128 + c0], edgeW[128 + c0 + 1]};
    const f32x2 w2 = {edgeW[256 + c0], edgeW[256 + c0 + 1]};
    const f32x2 w3 = {edgeW[384 + c0], edgeW[384 + c0 + 1]};
    const f32x2 eb = {edgeb[c0],       edgeb[c0 + 1]};

    const int beg = __builtin_amdgcn_readfirstlane(row_ptr[node]);
    const int end = __builtin_amdgcn_readfirstlane(row_ptr[node + 1]);

    const uint32 gs = hq[(size_t)node * 64 + lane];   // self-term early

    f32x2 accA = {0.f, 0.f}, accB = {0.f, 0.f};

#define EDGE(Q, G, ACC) {                                                     \
        f32x2 e = eb;                                                         \
        e += bflo((uint32)(Q).y) * w0;                                        \
        e += bfhi((uint32)(Q).y) * w1;                                        \
        e += bflo((uint32)(Q).z) * w2;                                        \
        e += bfhi((uint32)(Q).z) * w3;                                        \
        ACC.x += fmaxf(bflo(G) + e.x, 0.f);                                   \
        ACC.y += fmaxf(bfhi(G) + e.y, 0.f);                                   \
    }

    int i = beg;
    for (; i + 8 <= end; i += 8) {
        int4 q0 = adj[i + 0], q1 = adj[i + 1], q2 = adj[i + 2], q3 = adj[i + 3];
        int4 q4 = adj[i + 4], q5 = adj[i + 5], q6 = adj[i + 6], q7 = adj[i + 7];
        uint32 g0 = hq[(size_t)q0.x * 64 + lane];
        uint32 g1 = hq[(size_t)q1.x * 64 + lane];
        uint32 g2 = hq[(size_t)q2.x * 64 + lane];
        uint32 g3 = hq[(size_t)q3.x * 64 + lane];
        uint32 g4 = hq[(size_t)q4.x * 64 + lane];
        uint32 g5 = hq[(size_t)q5.x * 64 + lane];
        uint32 g6 = hq[(size_t)q6.x * 64 + lane];
        uint32 g7 = hq[(size_t)q7.x * 64 + lane];
        EDGE(q0, g0, accA); EDGE(q1, g1, accB);
        EDGE(q2, g2, accA); EDGE(q3, g3, accB);
        EDGE(q4, g4, accA); EDGE(q5, g5, accB);
        EDGE(q6, g6, accA); EDGE(q7, g7, accB);
    }
    for (; i + 4 <= end; i += 4) {
        int4 q0 = adj[i + 0], q1 = adj[i + 1], q2 = adj[i + 2], q3 = adj[i + 3];
        uint32 g0 = hq[(size_t)q0.x * 64 + lane];
        uint32 g1 = hq[(size_t)q1.x * 64 + lane];
        uint32 g2 = hq[(size_t)q2.x * 64 + lane];
        uint32 g3 = hq[(size_t)q3.x * 64 + lane];
        EDGE(q0, g0, accA); EDGE(q1, g1, accB);
        EDGE(q2, g2, accA); EDGE(q3, g3, accB);
    }
    for (; i < end; ++i) {
        int4 q = adj[i];
        uint32 g = hq[(size_t)q.x * 64 + lane];
        EDGE(q, g, accA);
    }
#undef EDGE

    const float ep = 1.0f + eps[l];
    float zl = fmaf(ep, bflo(gs), accA.x + accB.x);
    float zh = fmaf(ep, bfhi(gs), accA.y + accB.y);
    zq[(size_t)node * 64 + lane] = ((uint32)f2bf(zh) << 16) | (uint32)f2bf(zl);
}

// ---------------- MFMA MLP, operand-swapped ----------------
#define T_STRIDE 136   // shorts; 272B rows: 16B-aligned for b128 reads
__global__ __launch_bounds__(256) void mlp_mfma(
        const ushort16* __restrict__ zq,     // [N64][128] bf16
        const ushort16* __restrict__ Wb1t,   // [128 n][128 k] bf16
        const float* __restrict__ b1,
        const ushort16* __restrict__ Wb2t,
        const float* __restrict__ b2,
        ushort16* __restrict__ h_out, int N) {
    __shared__ ushort16 t_lds[64 * T_STRIDE];
    const int tid = threadIdx.x;
    const int w = tid >> 6, lane = tid & 63;
    const int c = lane & 15, g = lane >> 4;
    const int wrow0 = blockIdx.x * 64 + w * 16;   // node-tile base for this wave

    // ---- GEMM1: t^T = W1^T @ z^T ----
    const ushort16* zrow = zq + (size_t)(wrow0 + c) * HDIM + g * 8;
    short8 bf[4];
#pragma unroll
    for (int kk = 0; kk < 4; ++kk)
        bf[kk] = *(const short8*)(zrow + kk * 32);

    f32x4 acc[8];
#pragma unroll
    for (int n = 0; n < 8; ++n) {
        float4 bb = *(const float4*)(b1 + n * 16 + g * 4);
        acc[n] = (f32x4){bb.x, bb.y, bb.z, bb.w};
    }
#pragma unroll
    for (int kk = 0; kk < 4; ++kk) {
#pragma unroll
        for (int n = 0; n < 8; ++n) {
            short8 af = *(const short8*)(Wb1t + (size_t)(n * 16 + c) * HDIM + kk * 32 + g * 8);
            acc[n] = __builtin_amdgcn_mfma_f32_16x16x32_bf16(af, bf[kk], acc[n], 0, 0, 0);
        }
    }
#pragma unroll
    for (int n = 0; n < 8; ++n) {
        ushort4 u;
        u.x = f2bf(fmaxf(acc[n][0], 0.f));
        u.y = f2bf(fmaxf(acc[n][1], 0.f));
        u.z = f2bf(fmaxf(acc[n][2], 0.f));
        u.w = f2bf(fmaxf(acc[n][3], 0.f));
        *(ushort4*)(&t_lds[(w * 16 + c) * T_STRIDE + n * 16 + g * 4]) = u;
    }
    __syncthreads();

    // ---- GEMM2: h^T = W2^T @ t^T ----
    short8 bf2[4];
#pragma unroll
    for (int kk = 0; kk < 4; ++kk)
        bf2[kk] = *(const short8*)(&t_lds[(w * 16 + c) * T_STRIDE + kk * 32 + g * 8]);

    f32x4 acc2[8];
#pragma unroll
    for (int n = 0; n < 8; ++n) {
        float4 bb = *(const float4*)(b2 + n * 16 + g * 4);
        acc2[n] = (f32x4){bb.x, bb.y, bb.z, bb.w};
    }
#pragma unroll
    for (int kk = 0; kk < 4; ++kk) {
#pragma unroll
        for (int n = 0; n < 8; ++n) {
            short8 af = *(const short8*)(Wb2t + (size_t)(n * 16 + c) * HDIM + kk * 32 + g * 8);
            acc2[n] = __builtin_amdgcn_mfma_f32_16x16x32_bf16(af, bf2[kk], acc2[n], 0, 0, 0);
        }
    }
    if (wrow0 + c < N) {
#pragma unroll
        for (int n = 0; n < 8; ++n) {
            ushort4 u;
            u.x = f2bf(fmaxf(acc2[n][0], 0.f));
            u.y = f2bf(fmaxf(acc2[n][1], 0.f));
            u.z = f2bf(fmaxf(acc2[n][2], 0.f));
            u.w = f2bf(fmaxf(acc2[n][3], 0.f));
            *(ushort4*)(h_out + (size_t)(wrow0 + c) * HDIM + n * 16 + g * 4) = u;
        }
    }
}

// ---------------- output projection (reads bf16 h) ----------------
__global__ void out_kernel(const uint32* __restrict__ hq, const float* __restrict__ Wout,
                           const float* __restrict__ bout, float* __restrict__ out, int N) {
    int idx = blockIdx.x * 256 + threadIdx.x;
    int n = idx >> 4, pe = idx & 15;
    if (n >= N) return;
    float acc = bout[pe];
#pragma unroll 8
    for (int k2 = 0; k2 < 64; ++k2) {
        uint32 g = hq[(size_t)n * 64 + k2];
        acc = fmaf(bflo(g), Wout[(2 * k2) * 16 + pe], acc);
        acc = fmaf(bfhi(g), Wout[(2 * k2 + 1) * 16 + pe], acc);
    }
    out[(size_t)n * 16 + pe] = acc;
}

extern "C" void kernel_launch(void* const* d_in, const int* in_sizes, int n_in,
                              void* d_out, int out_size, void* d_ws, size_t ws_size,
                              hipStream_t stream) {
    const int*   x_type     = (const int*)  d_in[0];
    const float* x_feat     = (const float*)d_in[1];
    const int*   edge_index = (const int*)  d_in[2];
    const float* edge_attr  = (const float*)d_in[3];
    const float* type_embed = (const float*)d_in[4];
    const float* featW      = (const float*)d_in[5];
    const float* featb      = (const float*)d_in[6];
    const float* edgeW      = (const float*)d_in[7];
    const float* edgeb      = (const float*)d_in[8];
    const float* W1         = (const float*)d_in[9];
    const float* b1         = (const float*)d_in[10];
    const float* W2         = (const float*)d_in[11];
    const float* b2         = (const float*)d_in[12];
    const float* eps        = (const float*)d_in[13];
    const float* Wout       = (const float*)d_in[14];
    const float* bout       = (const float*)d_in[15];

    const int N = in_sizes[0];
    const int E = in_sizes[2] / 2;
    const int L = in_sizes[13];
    const int N64 = (N + 63) & ~63;     // pad node buffers so MFMA tiles read in-bounds
    const int NB  = (N + NPB - 1) / NPB;   // 196 buckets
    const int M   = NB * NCH;              // histogram matrix size

    const int* srcIdx = edge_index;
    const int* dstIdx = edge_index + E;

    auto align256 = [](size_t x) { return (x + 255) & ~(size_t)255; };
    char* p = (char*)d_ws;
    ushort16* h_buf  = (ushort16*)p;           p += align256((size_t)N64 * HDIM * 2);
    ushort16* z_buf  = (ushort16*)p;           p += align256((size_t)N64 * HDIM * 2);
    int*   row_ptr   = (int*)p;                p += align256((size_t)(N + 1) * 4);
    int*   histM     = (int*)p;                p += align256((size_t)M * 4);
    int*   Fscan     = (int*)p;                p += align256((size_t)M * 4);
    int*   partials  = (int*)p;                p += align256(1024 * 4);
    int*   offsets   = (int*)p;                p += align256(1024 * 4);
    int4*  tmp       = (int4*)p;               p += align256((size_t)E * 16);
    int4*  adj       = (int4*)p;               p += align256((size_t)E * 16);
    ushort16* Wb1t   = (ushort16*)p;           p += align256((size_t)L * HDIM * HDIM * 2);
    ushort16* Wb2t   = (ushort16*)p;           p += align256((size_t)L * HDIM * HDIM * 2);
    (void)ws_size;

    // ---- CSR build: counting sort, no global atomics ----
    hist_kernel<<<NCH, 256, 0, stream>>>(dstIdx, histM, E, NB);
    const int pblocks = (M + 255) / 256;            // 784
    partial_kernel<<<pblocks, 256, 0, stream>>>(histM, partials, M);
    scan_partials_kernel<<<1, 1024, 0, stream>>>(partials, offsets, pblocks);
    excl_out_kernel<<<pblocks, 256, 0, stream>>>(histM, offsets, Fscan, M);
    chunk_scatter_kernel<<<NCH, 256, 0, stream>>>(srcIdx, dstIdx, edge_attr, Fscan, tmp, E, NB);
    bucket_sort_kernel<<<NB, 256, 0, stream>>>(tmp, Fscan, row_ptr, adj, E, NB, N);

    const int wtotal = L * HDIM * HDIM;
    prep_weights<<<(wtotal + 255) / 256, 256, 0, stream>>>(W1, W2, Wb1t, Wb2t, wtotal);

    embed_kernel<<<((size_t)N * HDIM + 255) / 256, 256, 0, stream>>>(
        x_type, x_feat, type_embed, featW, featb, h_buf, N);

    for (int l = 0; l < L; ++l) {
        agg_kernel<<<(N + 1) / 2, 128, 0, stream>>>(
            (const uint32*)h_buf, row_ptr, adj, edgeW, edgeb, eps, l,
            (uint32*)z_buf, N);
        mlp_mfma<<<N64 / 64, 256, 0, stream>>>(
            z_buf, Wb1t + (size_t)l * HDIM * HDIM, b1 + (size_t)l * HDIM,
            Wb2t + (size_t)l * HDIM * HDIM, b2 + (size_t)l * HDIM, h_buf, N);
    }

    out_kernel<<<((size_t)N * 16 + 255) / 256, 256, 0, stream>>>(
        (const uint32*)h_buf, Wout, bout, (float*)d_out, N);
}

// Round 12
// 284.281 us; speedup vs baseline: 1.3872x; 1.0561x over previous
//
#include <hip/hip_runtime.h>
#include <hip/hip_bf16.h>

// ---------------------------------------------------------------------------
// EncoderGNN: 3-layer GINE encoder, N=50000, E=800000, H=128.
// Round 12: mlp_mfma re-gridded for occupancy — 1 wave (64 thd) per block,
// 16 rows/block, grid 3125, LDS 4.4KB/block -> ~32 waves/CU (was 782 blocks
// = 3/CU = 12 waves/CU, latency-bound at 18.7% occupancy, MfmaUtil 2.6%).
// Per-wave dataflow identical. CSR counting sort (r11) + r6 agg unchanged.
// ---------------------------------------------------------------------------

#define HDIM 128
#define NCH 1024          // histogram chunks
#define NPB 256           // nodes per bucket

typedef unsigned int uint32;
typedef unsigned short ushort16;
typedef __attribute__((ext_vector_type(8))) short short8;
typedef __attribute__((ext_vector_type(4))) float f32x4;
typedef __attribute__((ext_vector_type(2))) float f32x2;

__device__ __forceinline__ ushort16 f2bf(float f) {
    uint32 u = __float_as_uint(f);
    u += 0x7fff + ((u >> 16) & 1);      // round-to-nearest-even
    return (ushort16)(u >> 16);
}
__device__ __forceinline__ float bflo(uint32 g) { return __uint_as_float(g << 16); }
__device__ __forceinline__ float bfhi(uint32 g) { return __uint_as_float(g & 0xffff0000u); }

// ---------------- CSR build: counting sort ----------------
__global__ __launch_bounds__(256) void hist_kernel(const int* __restrict__ dstIdx,
                                                   int* __restrict__ histM, int E, int NB) {
    __shared__ int hist[256];
    const int b = blockIdx.x;
    for (int j = threadIdx.x; j < NB; j += 256) hist[j] = 0;
    __syncthreads();
    const int epb = (E + NCH - 1) / NCH;
    const int e0 = b * epb, e1 = min(e0 + epb, E);
    for (int e = e0 + threadIdx.x; e < e1; e += 256)
        atomicAdd(&hist[dstIdx[e] >> 8], 1);
    __syncthreads();
    for (int j = threadIdx.x; j < NB; j += 256)
        histM[j * NCH + b] = hist[j];
}

__global__ __launch_bounds__(256) void partial_kernel(const int* __restrict__ F,
                                                      int* __restrict__ partials, int M) {
    __shared__ int red[256];
    int i = blockIdx.x * 256 + threadIdx.x;
    red[threadIdx.x] = (i < M) ? F[i] : 0;
    __syncthreads();
#pragma unroll
    for (int off = 128; off > 0; off >>= 1) {
        if (threadIdx.x < off) red[threadIdx.x] += red[threadIdx.x + off];
        __syncthreads();
    }
    if (threadIdx.x == 0) partials[blockIdx.x] = red[0];
}

__global__ __launch_bounds__(1024) void scan_partials_kernel(const int* __restrict__ partials,
                                                             int* __restrict__ offsets, int nb) {
    __shared__ int buf[1024];
    int tid = threadIdx.x;
    int v0 = (tid < nb) ? partials[tid] : 0;
    buf[tid] = v0;
    __syncthreads();
#pragma unroll
    for (int off = 1; off < 1024; off <<= 1) {
        int v = (tid >= off) ? buf[tid - off] : 0;
        __syncthreads();
        buf[tid] += v;
        __syncthreads();
    }
    if (tid < nb) offsets[tid] = buf[tid] - v0;   // exclusive
}

__global__ __launch_bounds__(256) void excl_out_kernel(const int* __restrict__ F,
                                                       const int* __restrict__ offsets,
                                                       int* __restrict__ Fscan, int M) {
    __shared__ int buf[256];
    int tid = threadIdx.x;
    int i = blockIdx.x * 256 + tid;
    int v = (i < M) ? F[i] : 0;
    buf[tid] = v;
    __syncthreads();
#pragma unroll
    for (int off = 1; off < 256; off <<= 1) {
        int t = (tid >= off) ? buf[tid - off] : 0;
        __syncthreads();
        buf[tid] += t;
        __syncthreads();
    }
    if (i < M) Fscan[i] = buf[tid] - v + offsets[blockIdx.x];
}

__global__ __launch_bounds__(256) void chunk_scatter_kernel(
        const int* __restrict__ srcIdx, const int* __restrict__ dstIdx,
        const float* __restrict__ edge_attr, const int* __restrict__ Fscan,
        int4* __restrict__ tmp, int E, int NB) {
    __shared__ int cur[256];
    const int b = blockIdx.x;
    for (int j = threadIdx.x; j < NB; j += 256) cur[j] = Fscan[j * NCH + b];
    __syncthreads();
    const int epb = (E + NCH - 1) / NCH;
    const int e0 = b * epb, e1 = min(e0 + epb, E);
    for (int e = e0 + threadIdx.x; e < e1; e += 256) {
        int d = dstIdx[e];
        int r = atomicAdd(&cur[d >> 8], 1);
        float4 ea = *(const float4*)(edge_attr + (size_t)e * 4);
        int4 rec;
        rec.x = srcIdx[e];
        rec.y = (int)(((uint32)f2bf(ea.y) << 16) | (uint32)f2bf(ea.x));
        rec.z = (int)(((uint32)f2bf(ea.w) << 16) | (uint32)f2bf(ea.z));
        rec.w = d;
        tmp[r] = rec;
    }
}

__global__ __launch_bounds__(256) void bucket_sort_kernel(
        const int4* __restrict__ tmp, const int* __restrict__ Fscan,
        int* __restrict__ row_ptr, int4* __restrict__ adj, int E, int NB, int N) {
    __shared__ int cnt[256];
    __shared__ int cur[256];
    const int bkt = blockIdx.x;
    const int tid = threadIdx.x;
    const int base = Fscan[bkt * NCH];
    const int endb = (bkt + 1 < NB) ? Fscan[(bkt + 1) * NCH] : E;

    cnt[tid] = 0;
    __syncthreads();
    for (int i = base + tid; i < endb; i += 256)
        atomicAdd(&cnt[tmp[i].w & 255], 1);
    __syncthreads();
    int orig = cnt[tid];
#pragma unroll
    for (int off = 1; off < 256; off <<= 1) {
        int v = (tid >= off) ? cnt[tid - off] : 0;
        __syncthreads();
        cnt[tid] += v;
        __syncthreads();
    }
    int excl = cnt[tid] - orig;
    int node = bkt * NPB + tid;
    if (node <= N) row_ptr[node] = base + excl;
    cur[tid] = base + excl;
    __syncthreads();
    for (int i = base + tid; i < endb; i += 256) {
        int4 rec = tmp[i];
        int pos = atomicAdd(&cur[rec.w & 255], 1);
        adj[pos] = rec;
    }
}

// ---------------- weight prep: bf16 + transpose (once per call) ----------------
__global__ void prep_weights(const float* __restrict__ W1, const float* __restrict__ W2,
                             ushort16* __restrict__ Wb1t, ushort16* __restrict__ Wb2t, int total) {
    int idx = blockIdx.x * 256 + threadIdx.x;
    if (idx >= total) return;
    int l = idx >> 14;
    int rem = idx & 16383;
    int n = rem >> 7, k = rem & 127;
    size_t src = (size_t)l * 16384 + (size_t)k * 128 + n;
    size_t dst = (size_t)l * 16384 + (size_t)n * 128 + k;
    Wb1t[dst] = f2bf(W1[src]);
    Wb2t[dst] = f2bf(W2[src]);
}

// ---------------- node embedding (writes bf16 h) ----------------
__global__ void embed_kernel(const int* __restrict__ x_type, const float* __restrict__ x_feat,
                             const float* __restrict__ type_embed, const float* __restrict__ featW,
                             const float* __restrict__ featb, ushort16* __restrict__ h, int N) {
    int idx = blockIdx.x * 256 + threadIdx.x;
    int n = idx >> 7, c = idx & 127;
    if (n >= N) return;
    int t = x_type[n];
    float acc = type_embed[(size_t)t * HDIM + c] + featb[c];
#pragma unroll
    for (int k = 0; k < 7; ++k)
        acc = fmaf(x_feat[(size_t)n * 7 + k], featW[(size_t)k * HDIM + c], acc);
    h[(size_t)n * HDIM + c] = f2bf(acc);
}

// ---------------- aggregation: round-6 form (best measured) ----------------
__global__ __launch_bounds__(128) void agg_kernel(
        const uint32* __restrict__ hq,       // [N][64] packed bf16x2
        const int* __restrict__ row_ptr,
        const int4* __restrict__ adj,        // 16B records (uniform per wave)
        const float* __restrict__ edgeW, const float* __restrict__ edgeb,
        const float* __restrict__ eps, int l, uint32* __restrict__ zq, int N) {
    const int node = blockIdx.x * 2 + (threadIdx.x >> 6);
    const int lane = threadIdx.x & 63;
    if (node >= N) return;
    const int c0 = 2 * lane;
    const f32x2 w0 = {edgeW[c0],       edgeW[c0 + 1]};
    const f32x2 w1 = {edgeW[128 + c0], edgeW[128 + c0 + 1]};
    const f32x2 w2 = {edgeW[256 + c0], edgeW[256 + c0 + 1]};
    const f32x2 w3 = {edgeW[384 + c0], edgeW[384 + c0 + 1]};
    const f32x2 eb = {edgeb[c0],       edgeb[c0 + 1]};

    const int beg = __builtin_amdgcn_readfirstlane(row_ptr[node]);
    const int end = __builtin_amdgcn_readfirstlane(row_ptr[node + 1]);

    const uint32 gs = hq[(size_t)node * 64 + lane];   // self-term early

    f32x2 accA = {0.f, 0.f}, accB = {0.f, 0.f};

#define EDGE(Q, G, ACC) {                                                     \
        f32x2 e = eb;                                                         \
        e += bflo((uint32)(Q).y) * w0;                                        \
        e += bfhi((uint32)(Q).y) * w1;                                        \
        e += bflo((uint32)(Q).z) * w2;                                        \
        e += bfhi((uint32)(Q).z) * w3;                                        \
        ACC.x += fmaxf(bflo(G) + e.x, 0.f);                                   \
        ACC.y += fmaxf(bfhi(G) + e.y, 0.f);                                   \
    }

    int i = beg;
    for (; i + 8 <= end; i += 8) {
        int4 q0 = adj[i + 0], q1 = adj[i + 1], q2 = adj[i + 2], q3 = adj[i + 3];
        int4 q4 = adj[i + 4], q5 = adj[i + 5], q6 = adj[i + 6], q7 = adj[i + 7];
        uint32 g0 = hq[(size_t)q0.x * 64 + lane];
        uint32 g1 = hq[(size_t)q1.x * 64 + lane];
        uint32 g2 = hq[(size_t)q2.x * 64 + lane];
        uint32 g3 = hq[(size_t)q3.x * 64 + lane];
        uint32 g4 = hq[(size_t)q4.x * 64 + lane];
        uint32 g5 = hq[(size_t)q5.x * 64 + lane];
        uint32 g6 = hq[(size_t)q6.x * 64 + lane];
        uint32 g7 = hq[(size_t)q7.x * 64 + lane];
        EDGE(q0, g0, accA); EDGE(q1, g1, accB);
        EDGE(q2, g2, accA); EDGE(q3, g3, accB);
        EDGE(q4, g4, accA); EDGE(q5, g5, accB);
        EDGE(q6, g6, accA); EDGE(q7, g7, accB);
    }
    for (; i + 4 <= end; i += 4) {
        int4 q0 = adj[i + 0], q1 = adj[i + 1], q2 = adj[i + 2], q3 = adj[i + 3];
        uint32 g0 = hq[(size_t)q0.x * 64 + lane];
        uint32 g1 = hq[(size_t)q1.x * 64 + lane];
        uint32 g2 = hq[(size_t)q2.x * 64 + lane];
        uint32 g3 = hq[(size_t)q3.x * 64 + lane];
        EDGE(q0, g0, accA); EDGE(q1, g1, accB);
        EDGE(q2, g2, accA); EDGE(q3, g3, accB);
    }
    for (; i < end; ++i) {
        int4 q = adj[i];
        uint32 g = hq[(size_t)q.x * 64 + lane];
        EDGE(q, g, accA);
    }
#undef EDGE

    const float ep = 1.0f + eps[l];
    float zl = fmaf(ep, bflo(gs), accA.x + accB.x);
    float zh = fmaf(ep, bfhi(gs), accA.y + accB.y);
    zq[(size_t)node * 64 + lane] = ((uint32)f2bf(zh) << 16) | (uint32)f2bf(zl);
}

// ---------------- MFMA MLP, operand-swapped, 1 wave / 16 rows per block ----------------
#define T_STRIDE 136   // shorts; 272B rows: 16B-aligned for b128 reads
__global__ __launch_bounds__(64) void mlp_mfma(
        const ushort16* __restrict__ zq,     // [N64][128] bf16
        const ushort16* __restrict__ Wb1t,   // [128 n][128 k] bf16
        const float* __restrict__ b1,
        const ushort16* __restrict__ Wb2t,
        const float* __restrict__ b2,
        ushort16* __restrict__ h_out, int N) {
    __shared__ ushort16 t_lds[16 * T_STRIDE];
    const int lane = threadIdx.x & 63;
    const int c = lane & 15, g = lane >> 4;
    const int wrow0 = blockIdx.x * 16;            // node-tile base

    // ---- GEMM1: t^T = W1^T @ z^T ----
    const ushort16* zrow = zq + (size_t)(wrow0 + c) * HDIM + g * 8;
    short8 bf[4];
#pragma unroll
    for (int kk = 0; kk < 4; ++kk)
        bf[kk] = *(const short8*)(zrow + kk * 32);

    f32x4 acc[8];
#pragma unroll
    for (int n = 0; n < 8; ++n) {
        float4 bb = *(const float4*)(b1 + n * 16 + g * 4);
        acc[n] = (f32x4){bb.x, bb.y, bb.z, bb.w};
    }
#pragma unroll
    for (int kk = 0; kk < 4; ++kk) {
#pragma unroll
        for (int n = 0; n < 8; ++n) {
            short8 af = *(const short8*)(Wb1t + (size_t)(n * 16 + c) * HDIM + kk * 32 + g * 8);
            acc[n] = __builtin_amdgcn_mfma_f32_16x16x32_bf16(af, bf[kk], acc[n], 0, 0, 0);
        }
    }
#pragma unroll
    for (int n = 0; n < 8; ++n) {
        ushort4 u;
        u.x = f2bf(fmaxf(acc[n][0], 0.f));
        u.y = f2bf(fmaxf(acc[n][1], 0.f));
        u.z = f2bf(fmaxf(acc[n][2], 0.f));
        u.w = f2bf(fmaxf(acc[n][3], 0.f));
        *(ushort4*)(&t_lds[c * T_STRIDE + n * 16 + g * 4]) = u;
    }
    __syncthreads();

    // ---- GEMM2: h^T = W2^T @ t^T ----
    short8 bf2[4];
#pragma unroll
    for (int kk = 0; kk < 4; ++kk)
        bf2[kk] = *(const short8*)(&t_lds[c * T_STRIDE + kk * 32 + g * 8]);

    f32x4 acc2[8];
#pragma unroll
    for (int n = 0; n < 8; ++n) {
        float4 bb = *(const float4*)(b2 + n * 16 + g * 4);
        acc2[n] = (f32x4){bb.x, bb.y, bb.z, bb.w};
    }
#pragma unroll
    for (int kk = 0; kk < 4; ++kk) {
#pragma unroll
        for (int n = 0; n < 8; ++n) {
            short8 af = *(const short8*)(Wb2t + (size_t)(n * 16 + c) * HDIM + kk * 32 + g * 8);
            acc2[n] = __builtin_amdgcn_mfma_f32_16x16x32_bf16(af, bf2[kk], acc2[n], 0, 0, 0);
        }
    }
    if (wrow0 + c < N) {
#pragma unroll
        for (int n = 0; n < 8; ++n) {
            ushort4 u;
            u.x = f2bf(fmaxf(acc2[n][0], 0.f));
            u.y = f2bf(fmaxf(acc2[n][1], 0.f));
            u.z = f2bf(fmaxf(acc2[n][2], 0.f));
            u.w = f2bf(fmaxf(acc2[n][3], 0.f));
            *(ushort4*)(h_out + (size_t)(wrow0 + c) * HDIM + n * 16 + g * 4) = u;
        }
    }
}

// ---------------- output projection (reads bf16 h) ----------------
__global__ void out_kernel(const uint32* __restrict__ hq, const float* __restrict__ Wout,
                           const float* __restrict__ bout, float* __restrict__ out, int N) {
    int idx = blockIdx.x * 256 + threadIdx.x;
    int n = idx >> 4, pe = idx & 15;
    if (n >= N) return;
    float acc = bout[pe];
#pragma unroll 8
    for (int k2 = 0; k2 < 64; ++k2) {
        uint32 g = hq[(size_t)n * 64 + k2];
        acc = fmaf(bflo(g), Wout[(2 * k2) * 16 + pe], acc);
        acc = fmaf(bfhi(g), Wout[(2 * k2 + 1) * 16 + pe], acc);
    }
    out[(size_t)n * 16 + pe] = acc;
}

extern "C" void kernel_launch(void* const* d_in, const int* in_sizes, int n_in,
                              void* d_out, int out_size, void* d_ws, size_t ws_size,
                              hipStream_t stream) {
    const int*   x_type     = (const int*)  d_in[0];
    const float* x_feat     = (const float*)d_in[1];
    const int*   edge_index = (const int*)  d_in[2];
    const float* edge_attr  = (const float*)d_in[3];
    const float* type_embed = (const float*)d_in[4];
    const float* featW      = (const float*)d_in[5];
    const float* featb      = (const float*)d_in[6];
    const float* edgeW      = (const float*)d_in[7];
    const float* edgeb      = (const float*)d_in[8];
    const float* W1         = (const float*)d_in[9];
    const float* b1         = (const float*)d_in[10];
    const float* W2         = (const float*)d_in[11];
    const float* b2         = (const float*)d_in[12];
    const float* eps        = (const float*)d_in[13];
    const float* Wout       = (const float*)d_in[14];
    const float* bout       = (const float*)d_in[15];

    const int N = in_sizes[0];
    const int E = in_sizes[2] / 2;
    const int L = in_sizes[13];
    const int N64 = (N + 63) & ~63;        // padded node buffers
    const int NB  = (N + NPB - 1) / NPB;   // 196 buckets
    const int M   = NB * NCH;              // histogram matrix size

    const int* srcIdx = edge_index;
    const int* dstIdx = edge_index + E;

    auto align256 = [](size_t x) { return (x + 255) & ~(size_t)255; };
    char* p = (char*)d_ws;
    ushort16* h_buf  = (ushort16*)p;           p += align256((size_t)N64 * HDIM * 2);
    ushort16* z_buf  = (ushort16*)p;           p += align256((size_t)N64 * HDIM * 2);
    int*   row_ptr   = (int*)p;                p += align256((size_t)(N + 1) * 4);
    int*   histM     = (int*)p;                p += align256((size_t)M * 4);
    int*   Fscan     = (int*)p;                p += align256((size_t)M * 4);
    int*   partials  = (int*)p;                p += align256(1024 * 4);
    int*   offsets   = (int*)p;                p += align256(1024 * 4);
    int4*  tmp       = (int4*)p;               p += align256((size_t)E * 16);
    int4*  adj       = (int4*)p;               p += align256((size_t)E * 16);
    ushort16* Wb1t   = (ushort16*)p;           p += align256((size_t)L * HDIM * HDIM * 2);
    ushort16* Wb2t   = (ushort16*)p;           p += align256((size_t)L * HDIM * HDIM * 2);
    (void)ws_size;

    // ---- CSR build: counting sort, no global atomics ----
    hist_kernel<<<NCH, 256, 0, stream>>>(dstIdx, histM, E, NB);
    const int pblocks = (M + 255) / 256;            // 784
    partial_kernel<<<pblocks, 256, 0, stream>>>(histM, partials, M);
    scan_partials_kernel<<<1, 1024, 0, stream>>>(partials, offsets, pblocks);
    excl_out_kernel<<<pblocks, 256, 0, stream>>>(histM, offsets, Fscan, M);
    chunk_scatter_kernel<<<NCH, 256, 0, stream>>>(srcIdx, dstIdx, edge_attr, Fscan, tmp, E, NB);
    bucket_sort_kernel<<<NB, 256, 0, stream>>>(tmp, Fscan, row_ptr, adj, E, NB, N);

    const int wtotal = L * HDIM * HDIM;
    prep_weights<<<(wtotal + 255) / 256, 256, 0, stream>>>(W1, W2, Wb1t, Wb2t, wtotal);

    embed_kernel<<<((size_t)N * HDIM + 255) / 256, 256, 0, stream>>>(
        x_type, x_feat, type_embed, featW, featb, h_buf, N);

    const int mlp_blocks = (N + 15) / 16;   // 3125 one-wave blocks
    for (int l = 0; l < L; ++l) {
        agg_kernel<<<(N + 1) / 2, 128, 0, stream>>>(
            (const uint32*)h_buf, row_ptr, adj, edgeW, edgeb, eps, l,
            (uint32*)z_buf, N);
        mlp_mfma<<<mlp_blocks, 64, 0, stream>>>(
            z_buf, Wb1t + (size_t)l * HDIM * HDIM, b1 + (size_t)l * HDIM,
            Wb2t + (size_t)l * HDIM * HDIM, b2 + (size_t)l * HDIM, h_buf, N);
    }

    out_kernel<<<((size_t)N * 16 + 255) / 256, 256, 0, stream>>>(
        (const uint32*)h_buf, Wout, bout, (float*)d_out, N);
}